// Round 19
// baseline (479.588 us; speedup 1.0000x reference)
//
#include <hip/hip_runtime.h>
#include <math.h>

#define TT 16384
#define BB 4
#define CC 64
#define LL 30

typedef _Float16 f16;
typedef _Float16 f16x4 __attribute__((ext_vector_type(4)));
typedef _Float16 f16x8 __attribute__((ext_vector_type(8)));
typedef float f32x4 __attribute__((ext_vector_type(4)));
typedef unsigned int u32;

#define MFMA(a, b, c) __builtin_amdgcn_mfma_f32_16x16x32_f16(a, b, c, 0, 0, 0)

__device__ __forceinline__ float fsig(float x) { return 1.0f / (1.0f + __expf(-x)); }
__device__ __forceinline__ float ftanhf(float x) { return 1.0f - 2.0f / (__expf(2.0f * x) + 1.0f); }

__device__ __forceinline__ void gl_lds16(const void* g, void* l) {
    __builtin_amdgcn_global_load_lds((const __attribute__((address_space(1))) u32*)g,
                                     (__attribute__((address_space(3))) u32*)l, 16, 0, 0);
}

// ---------------- weight packing: A-side (row = out-channel) MFMA fragments ----------------
__global__ void pack_weights(const float* __restrict__ conv_w, const float* __restrict__ res_w,
                             const float* __restrict__ skip_w, const float* __restrict__ out0_w,
                             f16* __restrict__ wcv, f16* __restrict__ wrs, f16* __restrict__ wsk,
                             f16* __restrict__ wo0) {
    const int total_c = LL * 6 * 8 * 64 * 8;        // 737280
    const int total_r = (LL - 1) * 2 * 4 * 64 * 8;  // 118784
    const int total_s = LL * 2 * 4 * 64 * 8;        // 122880
    const int total_o = 2 * 4 * 64 * 8;             // 4096
    const int total = total_c + total_r + total_s + total_o;
    for (int i = blockIdx.x * blockDim.x + threadIdx.x; i < total; i += gridDim.x * blockDim.x) {
        if (i < total_c) {
            int e = i & 7, lane = (i >> 3) & 63, mf = (i >> 9) & 7, rest = i >> 12;
            int ks = rest % 6, l = rest / 6;
            int cin = (ks & 1) * 32 + (lane >> 4) * 8 + e;
            int tap = ks >> 1;
            int cout = mf * 16 + (lane & 15);
            wcv[i] = (f16)conv_w[(((size_t)l * 3 + tap) * 64 + cin) * 128 + cout];
        } else if (i < total_c + total_r) {
            int j = i - total_c;
            int e = j & 7, lane = (j >> 3) & 63, mf = (j >> 9) & 3, kk = (j >> 11) & 1, l = j >> 12;
            int cin = kk * 32 + (lane >> 4) * 8 + e;
            int cout = mf * 16 + (lane & 15);
            wrs[j] = (f16)res_w[((size_t)l * 64 + cin) * 64 + cout];
        } else if (i < total_c + total_r + total_s) {
            int j = i - total_c - total_r;
            int e = j & 7, lane = (j >> 3) & 63, mf = (j >> 9) & 3, kk = (j >> 11) & 1, l = j >> 12;
            int cin = kk * 32 + (lane >> 4) * 8 + e;
            int cout = mf * 16 + (lane & 15);
            wsk[j] = (f16)skip_w[((size_t)l * 64 + cin) * 64 + cout];
        } else {
            int j = i - total_c - total_r - total_s;
            int e = j & 7, lane = (j >> 3) & 63, mf = (j >> 9) & 3, kk = (j >> 11) & 1;
            int cin = kk * 32 + (lane >> 4) * 8 + e;  // k = cout of skip
            int c = mf * 16 + (lane & 15);
            wo0[j] = (f16)out0_w[cin * 64 + c];
        }
    }
}

// ---------------- x0 = relu(signal * in_w + in_b) -> f16 ----------------
__global__ void init_x_kernel(const float* __restrict__ signal, const float* __restrict__ in_w,
                              const float* __restrict__ in_b, f16* __restrict__ x0) {
    int i = blockIdx.x * 256 + threadIdx.x;  // < B*T*8
    int bt = i >> 3, g = i & 7;
    float s = signal[bt];
    f32x4 w0 = *(const f32x4*)&in_w[g * 8];
    f32x4 w1 = *(const f32x4*)&in_w[g * 8 + 4];
    f32x4 b0 = *(const f32x4*)&in_b[g * 8];
    f32x4 b1 = *(const f32x4*)&in_b[g * 8 + 4];
    f16x8 o;
#pragma unroll
    for (int j = 0; j < 4; ++j) {
        o[j] = (f16)fmaxf(s * w0[j] + b0[j], 0.f);
        o[4 + j] = (f16)fmaxf(s * w1[j] + b1[j], 0.f);
    }
    *(f16x8*)&x0[(size_t)bt * CC + g * 8] = o;
}

// ---------------- embed stage 1 (K-split): table + swish(pe0) -> h1[B][512] ----------------
__global__ void embed_stage1(const int* __restrict__ timestep, const float* __restrict__ pe0_w,
                             const float* __restrict__ pe0_b, float* __restrict__ h1) {
    __shared__ float emb[BB * 128];
    __shared__ float red[256];
    const int tid = threadIdx.x;
    for (int i = tid; i < BB * 128; i += 256) {
        int b = i >> 7, j = i & 127, jj = j & 63;
        float logit = (jj == 63) ? 1.0f : (float)jj * (1.0f / 63.0f);
        double e10 = pow(10.0, (double)(4.0f * logit));
        float comp = (float)e10 * (float)timestep[b];
        emb[i] = (j < 64) ? (float)sin((double)comp) : (float)cos((double)comp);
    }
    __syncthreads();
    const int c16 = tid & 15, b = (tid >> 4) & 3, part = tid >> 6;
    const int col = blockIdx.x * 16 + c16;
    float s = 0.f;
#pragma unroll
    for (int j = part * 32; j < part * 32 + 32; ++j)
        s += emb[b * 128 + j] * pe0_w[j * 512 + col];
    red[tid] = s;
    __syncthreads();
    if (part == 0) {
        float x = red[tid] + red[tid + 64] + red[tid + 128] + red[tid + 192] + pe0_b[col];
        h1[b * 512 + col] = x * fsig(x);
    }
}

// ---------------- embed stage 2 (K-split): swish(pe1) -> embed2[B][512] ----------------
__global__ void embed_stage2(const float* __restrict__ h1, const float* __restrict__ pe1_w,
                             const float* __restrict__ pe1_b, float* __restrict__ embed2) {
    __shared__ float hs[BB * 512];
    __shared__ float red[256];
    const int tid = threadIdx.x;
    for (int i = tid; i < BB * 512; i += 256) hs[i] = h1[i];
    __syncthreads();
    const int c8 = tid & 7, b = (tid >> 3) & 3, part = tid >> 5;
    const int col = blockIdx.x * 8 + c8;
    float s = 0.f;
#pragma unroll
    for (int j = part * 64; j < part * 64 + 64; ++j)
        s += hs[b * 512 + j] * pe1_w[j * 512 + col];
    red[tid] = s;
    __syncthreads();
    if (part == 0) {
        float x = pe1_b[col];
#pragma unroll
        for (int ph = 0; ph < 8; ++ph) x += red[ph * 32 + (tid & 31)];
        embed2[b * 512 + col] = x * fsig(x);
    }
}

// ---------------- e[l][b][64] = embed2[b] @ blk_emb_w[l] + blk_emb_b[l] ----------------
__global__ void e_kernel(const float* __restrict__ embed2, const float* __restrict__ blk_emb_w,
                         const float* __restrict__ blk_emb_b, float* __restrict__ e_out) {
    const int l = blockIdx.x, b = blockIdx.y;
    const int tid = threadIdx.x;
    __shared__ float em[512];
    __shared__ float red[256];
    for (int i = tid; i < 512; i += 256) em[i] = embed2[b * 512 + i];
    __syncthreads();
    const int c = tid & 63, part = tid >> 6;
    float s0 = 0.f, s1 = 0.f;
    for (int j = part * 128; j < part * 128 + 128; j += 2) {
        s0 += em[j] * blk_emb_w[((size_t)l * 512 + j) * 64 + c];
        s1 += em[j + 1] * blk_emb_w[((size_t)l * 512 + j + 1) * 64 + c];
    }
    red[tid] = s0 + s1;
    __syncthreads();
    if (tid < 64)
        e_out[(l * BB + b) * 64 + tid] =
            red[tid] + red[tid + 64] + red[tid + 128] + red[tid + 192] + blk_emb_b[l * 64 + tid];
}

// ---------------- evec[l][b][tap][128] = e @ conv_w[l][tap] (+conv_b at tap1) ----------------
__global__ void evec2_kernel(const float* __restrict__ e_in, const float* __restrict__ conv_w,
                             const float* __restrict__ conv_b, float* __restrict__ evec) {
    const int l = blockIdx.x, tap = blockIdx.y, b = blockIdx.z;
    const int n = threadIdx.x;  // 0..127
    __shared__ float es[64];
    if (n < 64) es[n] = e_in[(l * BB + b) * 64 + n];
    __syncthreads();
    const float* cw = conv_w + ((size_t)(l * 3 + tap) * 64) * 128;
    float a0 = 0.f, a1 = 0.f, a2 = 0.f, a3 = 0.f;
#pragma unroll
    for (int k = 0; k < 64; k += 4) {
        a0 += es[k] * cw[k * 128 + n];
        a1 += es[k + 1] * cw[(k + 1) * 128 + n];
        a2 += es[k + 2] * cw[(k + 2) * 128 + n];
        a3 += es[k + 3] * cw[(k + 3) * 128 + n];
    }
    float s = a0 + a1 + a2 + a3 + ((tap == 1) ? conv_b[l * 128 + n] : 0.f);
    evec[((size_t)(l * 4 + b) * 3 + tap) * 128 + n] = s;
}

// ---------------- sum of skip biases over layers ----------------
__global__ void sbsum_kernel(const float* __restrict__ skip_b, float* __restrict__ sbsum) {
    int c = threadIdx.x;  // 64
    float s = 0.f;
    for (int l = 0; l < LL; ++l) s += skip_b[l * 64 + c];
    sbsum[c] = s;
}

// ---------------- single-layer kernel (round-16 proven: 64 rows, XCD swizzle) ----------------
__launch_bounds__(256, 5)
__global__ void layer_kernel(const f16* __restrict__ xin, f16* __restrict__ xout,
                             f16* __restrict__ zg,
                             const f16* __restrict__ wcv, const f16* __restrict__ wrs,
                             const float* __restrict__ evec_l, const float* __restrict__ res_b,
                             const f16* __restrict__ zpage, int d) {
    extern __shared__ f16 lds[];
    const int tid = threadIdx.x, lane = tid & 63, w = tid >> 6;
    const int lrow = lane & 15, lk = lane >> 4;
    const int lin = blockIdx.x;
    const int lin2 = (lin & 7) * 128 + (lin >> 3);
    const int b = lin2 >> 8, t0 = (lin2 & 255) * 64;
    const int stride = (d < 64) ? d : 64;
    const int R8 = (64 + 2 * stride + 7) & ~7;
    f16* xs = lds;
    f16* zs = lds + R8 * 64;
    const f16* xb = xin + (size_t)b * TT * CC;
    f16* zb = zg + (size_t)b * TT * CC;

    const int NCH = R8 >> 3;
    for (int chunk = w; chunk < NCH; chunk += 4) {
        int gid = chunk * 64 + lane;
        int r = gid >> 3, g = gid & 7;
        int t = t0 - d + r + ((d > 64) ? ((r >> 6) * (d - 64)) : 0);
        const f16* src = ((unsigned)t < TT) ? (xb + (size_t)t * CC + ((g ^ (r & 7)) << 3)) : zpage;
        gl_lds16(src, (void*)((char*)xs + chunk * 1024));
    }
    __syncthreads();

    f32x4 acc[2][4] = {};
#pragma unroll
    for (int ks = 0; ks < 6; ++ks) {
        const int tap = ks >> 1, kk = ks & 1;
        f16x8 aw0 = *(const f16x8*)&wcv[((ks * 8 + w) * 64 + lane) * 8];
        f16x8 aw1 = *(const f16x8*)&wcv[((ks * 8 + w + 4) * 64 + lane) * 8];
#pragma unroll
        for (int nfi = 0; nfi < 4; ++nfi) {
            int r = nfi * 16 + lrow + tap * stride;
            int g = kk * 4 + lk;
            f16x8 bx = *(const f16x8*)&xs[r * 64 + ((g ^ (r & 7)) << 3)];
            acc[0][nfi] = MFMA(aw0, bx, acc[0][nfi]);
            acc[1][nfi] = MFMA(aw1, bx, acc[1][nfi]);
        }
    }

    const float* evb = evec_l + b * 384;
    const int ca = w * 16 + lk * 4;
    const int gz = ca >> 3;
    f32x4 e0a = *(const f32x4*)&evb[ca], e1a = *(const f32x4*)&evb[128 + ca],
          e2a = *(const f32x4*)&evb[256 + ca];
    f32x4 e0b = *(const f32x4*)&evb[64 + ca], e1b = *(const f32x4*)&evb[192 + ca],
          e2b = *(const f32x4*)&evb[320 + ca];
#pragma unroll
    for (int nfi = 0; nfi < 4; ++nfi) {
        int trow = nfi * 16 + lrow;
        int t = t0 + trow;
        float m0 = (t >= d) ? 1.f : 0.f;
        float m2 = (t + d < TT) ? 1.f : 0.f;
        f16x4 zo;
#pragma unroll
        for (int r = 0; r < 4; ++r) {
            float ya = acc[0][nfi][r] + e1a[r] + m0 * e0a[r] + m2 * e2a[r];
            float yb = acc[1][nfi][r] + e1b[r] + m0 * e0b[r] + m2 * e2b[r];
            zo[r] = (f16)(ftanhf(ya) * fsig(yb));
        }
        *(f16x4*)&zs[trow * 64 + ((gz ^ (trow & 7)) << 3) + (ca & 7)] = zo;
        *(f16x4*)&zb[(size_t)(t0 + trow) * CC + ca] = zo;
    }

    if (wrs != nullptr) {
        __syncthreads();
        f32x4 accR[4] = {};
#pragma unroll
        for (int kk = 0; kk < 2; ++kk) {
            f16x8 ar_ = *(const f16x8*)&wrs[((kk * 4 + w) * 64 + lane) * 8];
#pragma unroll
            for (int nfi = 0; nfi < 4; ++nfi) {
                int trow = nfi * 16 + lrow;
                int g = kk * 4 + lk;
                f16x8 bz = *(const f16x8*)&zs[trow * 64 + ((g ^ (trow & 7)) << 3)];
                accR[nfi] = MFMA(ar_, bz, accR[nfi]);
            }
        }
        f16* xob = xout + (size_t)b * TT * CC;
        f32x4 rb4 = *(const f32x4*)&res_b[ca];
#pragma unroll
        for (int nfi = 0; nfi < 4; ++nfi) {
            int trow = nfi * 16 + lrow;
            int rr = stride + trow;
            f16x4 xv = *(const f16x4*)&xs[rr * 64 + ((gz ^ (rr & 7)) << 3) + (ca & 7)];
            f16x4 xo;
#pragma unroll
            for (int r = 0; r < 4; ++r)
                xo[r] = (f16)((accR[nfi][r] + rb4[r] + (float)xv[r]) * 0.70710678118654752f);
            *(f16x4*)&xob[(size_t)(t0 + trow) * CC + ca] = xo;
        }
    }
}

// ---------------- fused 2-layer pair kernel (small dilations D1, D2) ----------------
template <int D1, int D2>
__launch_bounds__(256, 4)
__global__ void pair_kernel(const f16* __restrict__ xin, f16* __restrict__ xout,
                            f16* __restrict__ zg1, f16* __restrict__ zg2,
                            const f16* __restrict__ wcv1, const f16* __restrict__ wcv2,
                            const f16* __restrict__ wrs1, const f16* __restrict__ wrs2,
                            const float* __restrict__ evec1, const float* __restrict__ evec2,
                            const float* __restrict__ resb1, const float* __restrict__ resb2,
                            const f16* __restrict__ zpage) {
    constexpr int H = D1 + D2;
    constexpr int RX = 64 + 2 * H;
    constexpr int R8X = (RX + 7) & ~7;
    constexpr int NT = (RX + 15) / 16;
    constexpr int ZR = NT * 16;
    __shared__ f16 xs[R8X * 64];
    __shared__ f16 zs[ZR * 64];
    __shared__ f16 xn[ZR * 64];
    f16* z2 = xs;  // alias: x dead after res-i phase

    const int tid = threadIdx.x, lane = tid & 63, w = tid >> 6;
    const int lrow = lane & 15, lk = lane >> 4;
    const int lin = blockIdx.x;  // 1024 = 8 XCD x 128
    const int lin2 = (lin & 7) * 128 + (lin >> 3);
    const int b = lin2 >> 8, t0 = (lin2 & 255) * 64;
    const f16* xb = xin + (size_t)b * TT * CC;
    f16* zb1 = zg1 + (size_t)b * TT * CC;
    f16* zb2 = zg2 + (size_t)b * TT * CC;
    f16* xob = xout + (size_t)b * TT * CC;
    const int ca = w * 16 + lk * 4, gz = ca >> 3;

    const int NCH = R8X >> 3;
    for (int chunk = w; chunk < NCH; chunk += 4) {
        int gid = chunk * 64 + lane;
        int r = gid >> 3, g = gid & 7;
        int t = t0 - H + r;
        const f16* src = ((unsigned)t < TT) ? (xb + (size_t)t * CC + ((g ^ (r & 7)) << 3)) : zpage;
        gl_lds16(src, (void*)((char*)xs + chunk * 1024));
    }
    __syncthreads();

    {
        f32x4 acc[2][NT] = {};
#pragma unroll
        for (int ks = 0; ks < 6; ++ks) {
            const int tap = ks >> 1, kk = ks & 1;
            f16x8 aw0 = *(const f16x8*)&wcv1[((ks * 8 + w) * 64 + lane) * 8];
            f16x8 aw1 = *(const f16x8*)&wcv1[((ks * 8 + w + 4) * 64 + lane) * 8];
#pragma unroll
            for (int nfi = 0; nfi < NT; ++nfi) {
                int rx = nfi * 16 + lrow + (tap - 1) * D1;
                rx = (rx < 0) ? 0 : ((rx > R8X - 1) ? (R8X - 1) : rx);
                int g = kk * 4 + lk;
                f16x8 bx = *(const f16x8*)&xs[rx * 64 + ((g ^ (rx & 7)) << 3)];
                acc[0][nfi] = MFMA(aw0, bx, acc[0][nfi]);
                acc[1][nfi] = MFMA(aw1, bx, acc[1][nfi]);
            }
        }
        const float* evb = evec1 + b * 384;
        f32x4 e0a = *(const f32x4*)&evb[ca], e1a = *(const f32x4*)&evb[128 + ca],
              e2a = *(const f32x4*)&evb[256 + ca];
        f32x4 e0b = *(const f32x4*)&evb[64 + ca], e1b = *(const f32x4*)&evb[192 + ca],
              e2b = *(const f32x4*)&evb[320 + ca];
#pragma unroll
        for (int nfi = 0; nfi < NT; ++nfi) {
            int rt = nfi * 16 + lrow;
            int tz = t0 - H + rt;
            bool valid = ((unsigned)tz < TT);
            float m0 = (tz >= D1) ? 1.f : 0.f;
            float m2 = (tz + D1 < TT) ? 1.f : 0.f;
            f16x4 zo;
#pragma unroll
            for (int r = 0; r < 4; ++r) {
                float ya = acc[0][nfi][r] + e1a[r] + m0 * e0a[r] + m2 * e2a[r];
                float yb = acc[1][nfi][r] + e1b[r] + m0 * e0b[r] + m2 * e2b[r];
                zo[r] = valid ? (f16)(ftanhf(ya) * fsig(yb)) : (f16)0;
            }
            *(f16x4*)&zs[rt * 64 + ((gz ^ (rt & 7)) << 3) + (ca & 7)] = zo;
            if (rt >= H && rt < H + 64) *(f16x4*)&zb1[(size_t)tz * CC + ca] = zo;
        }
    }
    __syncthreads();

    {
        f32x4 accR[NT] = {};
#pragma unroll
        for (int kk = 0; kk < 2; ++kk) {
            f16x8 ar_ = *(const f16x8*)&wrs1[((kk * 4 + w) * 64 + lane) * 8];
#pragma unroll
            for (int nfi = 0; nfi < NT; ++nfi) {
                int rt = nfi * 16 + lrow;
                int g = kk * 4 + lk;
                f16x8 bz = *(const f16x8*)&zs[rt * 64 + ((g ^ (rt & 7)) << 3)];
                accR[nfi] = MFMA(ar_, bz, accR[nfi]);
            }
        }
        f32x4 rb4 = *(const f32x4*)&resb1[ca];
#pragma unroll
        for (int nfi = 0; nfi < NT; ++nfi) {
            int rt = nfi * 16 + lrow;
            int tz = t0 - H + rt;
            bool valid = ((unsigned)tz < TT);
            int rxc = (rt > R8X - 1) ? (R8X - 1) : rt;
            f16x4 xv = *(const f16x4*)&xs[rxc * 64 + ((gz ^ (rxc & 7)) << 3) + (ca & 7)];
            f16x4 xo;
#pragma unroll
            for (int r = 0; r < 4; ++r)
                xo[r] = valid ? (f16)((accR[nfi][r] + rb4[r] + (float)xv[r]) * 0.70710678118654752f)
                              : (f16)0;
            *(f16x4*)&xn[rt * 64 + ((gz ^ (rt & 7)) << 3) + (ca & 7)] = xo;
        }
    }
    __syncthreads();

    {
        f32x4 acc[2][4] = {};
#pragma unroll
        for (int ks = 0; ks < 6; ++ks) {
            const int tap = ks >> 1, kk = ks & 1;
            f16x8 aw0 = *(const f16x8*)&wcv2[((ks * 8 + w) * 64 + lane) * 8];
            f16x8 aw1 = *(const f16x8*)&wcv2[((ks * 8 + w + 4) * 64 + lane) * 8];
#pragma unroll
            for (int nfi = 0; nfi < 4; ++nfi) {
                int rxn = nfi * 16 + lrow + H + (tap - 1) * D2;
                int g = kk * 4 + lk;
                f16x8 bx = *(const f16x8*)&xn[rxn * 64 + ((g ^ (rxn & 7)) << 3)];
                acc[0][nfi] = MFMA(aw0, bx, acc[0][nfi]);
                acc[1][nfi] = MFMA(aw1, bx, acc[1][nfi]);
            }
        }
        const float* evb = evec2 + b * 384;
        f32x4 e0a = *(const f32x4*)&evb[ca], e1a = *(const f32x4*)&evb[128 + ca],
              e2a = *(const f32x4*)&evb[256 + ca];
        f32x4 e0b = *(const f32x4*)&evb[64 + ca], e1b = *(const f32x4*)&evb[192 + ca],
              e2b = *(const f32x4*)&evb[320 + ca];
#pragma unroll
        for (int nfi = 0; nfi < 4; ++nfi) {
            int trow = nfi * 16 + lrow;
            int t = t0 + trow;
            float m0 = (t >= D2) ? 1.f : 0.f;
            float m2 = (t + D2 < TT) ? 1.f : 0.f;
            f16x4 zo;
#pragma unroll
            for (int r = 0; r < 4; ++r) {
                float ya = acc[0][nfi][r] + e1a[r] + m0 * e0a[r] + m2 * e2a[r];
                float yb = acc[1][nfi][r] + e1b[r] + m0 * e0b[r] + m2 * e2b[r];
                zo[r] = (f16)(ftanhf(ya) * fsig(yb));
            }
            *(f16x4*)&z2[trow * 64 + ((gz ^ (trow & 7)) << 3) + (ca & 7)] = zo;
            *(f16x4*)&zb2[(size_t)t * CC + ca] = zo;
        }
    }
    __syncthreads();

    {
        f32x4 accR[4] = {};
#pragma unroll
        for (int kk = 0; kk < 2; ++kk) {
            f16x8 ar_ = *(const f16x8*)&wrs2[((kk * 4 + w) * 64 + lane) * 8];
#pragma unroll
            for (int nfi = 0; nfi < 4; ++nfi) {
                int trow = nfi * 16 + lrow;
                int g = kk * 4 + lk;
                f16x8 bz = *(const f16x8*)&z2[trow * 64 + ((g ^ (trow & 7)) << 3)];
                accR[nfi] = MFMA(ar_, bz, accR[nfi]);
            }
        }
        f32x4 rb4 = *(const f32x4*)&resb2[ca];
#pragma unroll
        for (int nfi = 0; nfi < 4; ++nfi) {
            int trow = nfi * 16 + lrow;
            int rr = trow + H;
            f16x4 xv = *(const f16x4*)&xn[rr * 64 + ((gz ^ (rr & 7)) << 3) + (ca & 7)];
            f16x4 xo;
#pragma unroll
            for (int r = 0; r < 4; ++r)
                xo[r] = (f16)((accR[nfi][r] + rb4[r] + (float)xv[r]) * 0.70710678118654752f);
            *(f16x4*)&xob[(size_t)(t0 + trow) * CC + ca] = xo;
        }
    }
}

// ---------------- deferred skip reduction + output head: 2 layers per barrier ----------------
__launch_bounds__(256)
__global__ void skip_head(const f16* __restrict__ zbuf, const f16* __restrict__ z29,
                          const f16* __restrict__ wsk, const f16* __restrict__ wo0,
                          const float* __restrict__ sbsum, const float* __restrict__ out0_b,
                          const float* __restrict__ out1_w, const float* __restrict__ out1_b,
                          float* __restrict__ out) {
    __shared__ f16 zb[4][64 * 64];  // 32 KB rotation
    const int tid = threadIdx.x, lane = tid & 63, w = tid >> 6;
    const int lrow = lane & 15, lk = lane >> 4;
    const int lin = blockIdx.x;  // 1024 = 8 XCD x 128
    const int lin2 = (lin & 7) * 128 + (lin >> 3);
    const int b = lin2 >> 8, tile = lin2 & 255;
    const int t0 = tile * 64;

#define STAGE_Z(L, BUF)                                                                       \
    {                                                                                         \
        const f16* zl =                                                                       \
            (((L) < LL - 1) ? (zbuf + (size_t)(L)*BB * TT * CC) : z29) + (size_t)b * TT * CC; \
        _Pragma("unroll") for (int j = 0; j < 2; ++j) {                                       \
            int chunk = j * 4 + w;                                                            \
            int gid = chunk * 64 + lane;                                                      \
            int r = gid >> 3, g = gid & 7;                                                    \
            gl_lds16(zl + (size_t)(t0 + r) * CC + ((g ^ (r & 7)) << 3),                       \
                     (void*)((char*)zb[BUF] + chunk * 1024));                                 \
        }                                                                                     \
    }

    f32x4 accS[4] = {};
    STAGE_Z(0, 0);
    STAGE_Z(1, 1);
    for (int l = 0; l < LL; l += 2) {  // LL even: layers l, l+1 per iteration
        __syncthreads();               // drains staged loads for l, l+1; prior reads done
        if (l + 2 < LL) STAGE_Z(l + 2, (l + 2) & 3);
        if (l + 3 < LL) STAGE_Z(l + 3, (l + 3) & 3);
#pragma unroll
        for (int s = 0; s < 2; ++s) {
            const f16* wl = wsk + (size_t)(l + s) * 4096;
            const f16* zcur = zb[(l + s) & 3];
#pragma unroll
            for (int kk = 0; kk < 2; ++kk) {
                f16x8 as_ = *(const f16x8*)&wl[((kk * 4 + w) * 64 + lane) * 8];
#pragma unroll
                for (int nt = 0; nt < 4; ++nt) {
                    int trow = nt * 16 + lrow;
                    int g = kk * 4 + lk;
                    f16x8 bz = *(const f16x8*)&zcur[trow * 64 + ((g ^ (trow & 7)) << 3)];
                    accS[nt] = MFMA(as_, bz, accS[nt]);
                }
            }
        }
    }

    __syncthreads();
    const float invL = 0.18257418583505537f;  // 1/sqrt(30)
    const int cb = w * 16 + lk * 4;
    const int gz = cb >> 3;
    f32x4 sb4 = *(const f32x4*)&sbsum[cb];
#pragma unroll
    for (int nt = 0; nt < 4; ++nt) {
        int row = nt * 16 + lrow;
        f16x4 sn;
#pragma unroll
        for (int r = 0; r < 4; ++r) sn[r] = (f16)((accS[nt][r] + sb4[r]) * invL);
        *(f16x4*)&zb[0][row * 64 + ((gz ^ (row & 7)) << 3) + (cb & 7)] = sn;
    }
    __syncthreads();

    const int trow = w * 16 + lrow;
    f32x4 accO[4] = {};
#pragma unroll
    for (int kk = 0; kk < 2; ++kk) {
        int g = kk * 4 + lk;
        f16x8 bz = *(const f16x8*)&zb[0][trow * 64 + ((g ^ (trow & 7)) << 3)];
#pragma unroll
        for (int mf = 0; mf < 4; ++mf) {
            f16x8 aw = *(const f16x8*)&wo0[((kk * 4 + mf) * 64 + lane) * 8];
            accO[mf] = MFMA(aw, bz, accO[mf]);
        }
    }
    float pv = 0.f;
    const float b1 = out1_b[0];
#pragma unroll
    for (int mf = 0; mf < 4; ++mf) {
        int c = mf * 16 + lk * 4;
        f32x4 b0 = *(const f32x4*)&out0_b[c];
        f32x4 w1 = *(const f32x4*)&out1_w[c];
#pragma unroll
        for (int r = 0; r < 4; ++r) pv += fmaxf(accO[mf][r] + b0[r], 0.f) * w1[r];
    }
    pv += __shfl_xor(pv, 16);
    pv += __shfl_xor(pv, 32);
    if (lane < 16) out[(size_t)b * TT + t0 + w * 16 + lane] = pv + b1;
#undef STAGE_Z
}

extern "C" void kernel_launch(void* const* d_in, const int* in_sizes, int n_in,
                              void* d_out, int out_size, void* d_ws, size_t ws_size,
                              hipStream_t stream) {
    const float* signal = (const float*)d_in[0];
    const int* timestep = (const int*)d_in[1];
    const float* in_w = (const float*)d_in[2];
    const float* in_b = (const float*)d_in[3];
    const float* pe0_w = (const float*)d_in[4];
    const float* pe0_b = (const float*)d_in[5];
    const float* pe1_w = (const float*)d_in[6];
    const float* pe1_b = (const float*)d_in[7];
    const float* blk_emb_w = (const float*)d_in[8];
    const float* blk_emb_b = (const float*)d_in[9];
    const float* blk_conv_w = (const float*)d_in[10];
    const float* blk_conv_b = (const float*)d_in[11];
    const float* blk_res_w = (const float*)d_in[12];
    const float* blk_res_b = (const float*)d_in[13];
    const float* blk_skip_w = (const float*)d_in[14];
    const float* blk_skip_b = (const float*)d_in[15];
    const float* out0_w = (const float*)d_in[16];
    const float* out0_b = (const float*)d_in[17];
    const float* out1_w = (const float*)d_in[18];
    const float* out1_b = (const float*)d_in[19];

    char* p = (char*)d_ws;
    const size_t xhsz = (size_t)BB * TT * CC * sizeof(f16);  // 8 MiB
    const size_t BTC = (size_t)BB * TT * CC;
    f16* xa = (f16*)p; p += xhsz;
    f16* xb2 = (f16*)p; p += xhsz;
    f16* wcv = (f16*)p; p += (size_t)737280 * 2;
    f16* wrs = (f16*)p; p += (size_t)118784 * 2;
    f16* wsk = (f16*)p; p += (size_t)122880 * 2;
    f16* wo0 = (f16*)p; p += (size_t)4096 * 2;
    float* h1 = (float*)p; p += 4 * 512 * sizeof(float);
    float* embed2 = (float*)p; p += 4 * 512 * sizeof(float);
    float* e_buf = (float*)p; p += (size_t)LL * BB * 64 * sizeof(float);
    float* evec = (float*)p; p += (size_t)LL * 4 * 3 * 128 * sizeof(float);
    float* sbsum = (float*)p; p += 64 * sizeof(float);
    f16* zpage = (f16*)p; p += 256;
    p = (char*)(((size_t)p + 255) & ~(size_t)255);
    f16* zbuf = (f16*)p; p += (size_t)(LL - 1) * xhsz;  // layers 0..28; layer 29's z -> dead buf

    hipMemsetAsync(zpage, 0, 256, stream);
    pack_weights<<<1024, 256, 0, stream>>>(blk_conv_w, blk_res_w, blk_skip_w, out0_w,
                                           wcv, wrs, wsk, wo0);
    init_x_kernel<<<2048, 256, 0, stream>>>(signal, in_w, in_b, xa);
    embed_stage1<<<32, 256, 0, stream>>>(timestep, pe0_w, pe0_b, h1);
    embed_stage2<<<64, 256, 0, stream>>>(h1, pe1_w, pe1_b, embed2);
    e_kernel<<<dim3(LL, BB), 256, 0, stream>>>(embed2, blk_emb_w, blk_emb_b, e_buf);
    evec2_kernel<<<dim3(LL, 3, BB), 128, 0, stream>>>(e_buf, blk_conv_w, blk_conv_b, evec);
    sbsum_kernel<<<1, 64, 0, stream>>>(blk_skip_b, sbsum);

    f16* cur = xa;
    f16* nxt = xb2;
    f16* z29 = xa;
    for (int c = 0; c < 3; ++c) {
        const int l0 = c * 10;
        pair_kernel<1, 2><<<1024, 256, 0, stream>>>(
            cur, nxt, zbuf + (size_t)l0 * BTC, zbuf + (size_t)(l0 + 1) * BTC,
            wcv + (size_t)l0 * 24576, wcv + (size_t)(l0 + 1) * 24576,
            wrs + (size_t)l0 * 4096, wrs + (size_t)(l0 + 1) * 4096,
            evec + (size_t)l0 * 1536, evec + (size_t)(l0 + 1) * 1536,
            blk_res_b + l0 * 64, blk_res_b + (l0 + 1) * 64, zpage);
        { f16* t = cur; cur = nxt; nxt = t; }
        pair_kernel<4, 8><<<1024, 256, 0, stream>>>(
            cur, nxt, zbuf + (size_t)(l0 + 2) * BTC, zbuf + (size_t)(l0 + 3) * BTC,
            wcv + (size_t)(l0 + 2) * 24576, wcv + (size_t)(l0 + 3) * 24576,
            wrs + (size_t)(l0 + 2) * 4096, wrs + (size_t)(l0 + 3) * 4096,
            evec + (size_t)(l0 + 2) * 1536, evec + (size_t)(l0 + 3) * 1536,
            blk_res_b + (l0 + 2) * 64, blk_res_b + (l0 + 3) * 64, zpage);
        { f16* t = cur; cur = nxt; nxt = t; }
        for (int i = l0 + 4; i < l0 + 10; ++i) {
            int d = 1 << (i % 10);
            bool last = (i == LL - 1);
            f16* zg = last ? nxt : (zbuf + (size_t)i * BTC);
            if (last) z29 = nxt;
            int stride = (d < 64) ? d : 64;
            int R8 = (64 + 2 * stride + 7) & ~7;
            size_t smem = (size_t)(R8 * 64 + 64 * 64) * sizeof(f16);
            layer_kernel<<<BB * (TT / 64), 256, smem, stream>>>(
                cur, nxt, zg, wcv + (size_t)i * 24576,
                last ? nullptr : (wrs + (size_t)i * 4096), evec + (size_t)i * 1536,
                last ? nullptr : (blk_res_b + i * 64), zpage, d);
            if (!last) { f16* t = cur; cur = nxt; nxt = t; }
        }
    }

    skip_head<<<(BB * TT) / 64, 256, 0, stream>>>(zbuf, z29, wsk, wo0, sbsum, out0_b, out1_w,
                                                  out1_b, (float*)d_out);
}

// Round 20
// 471.674 us; speedup vs baseline: 1.0168x; 1.0168x over previous
//
#include <hip/hip_runtime.h>
#include <math.h>

#define TT 16384
#define BB 4
#define CC 64
#define LL 30

typedef _Float16 f16;
typedef _Float16 f16x4 __attribute__((ext_vector_type(4)));
typedef _Float16 f16x8 __attribute__((ext_vector_type(8)));
typedef float f32x4 __attribute__((ext_vector_type(4)));
typedef unsigned int u32;

#define MFMA(a, b, c) __builtin_amdgcn_mfma_f32_16x16x32_f16(a, b, c, 0, 0, 0)

__device__ __forceinline__ float fsig(float x) { return 1.0f / (1.0f + __expf(-x)); }
__device__ __forceinline__ float ftanhf(float x) { return 1.0f - 2.0f / (__expf(2.0f * x) + 1.0f); }

__device__ __forceinline__ void gl_lds16(const void* g, void* l) {
    __builtin_amdgcn_global_load_lds((const __attribute__((address_space(1))) u32*)g,
                                     (__attribute__((address_space(3))) u32*)l, 16, 0, 0);
}

// ---------------- weight packing: A-side (row = out-channel) MFMA fragments ----------------
__global__ void pack_weights(const float* __restrict__ conv_w, const float* __restrict__ res_w,
                             const float* __restrict__ skip_w, const float* __restrict__ out0_w,
                             f16* __restrict__ wcv, f16* __restrict__ wrs, f16* __restrict__ wsk,
                             f16* __restrict__ wo0) {
    const int total_c = LL * 6 * 8 * 64 * 8;        // 737280
    const int total_r = (LL - 1) * 2 * 4 * 64 * 8;  // 118784
    const int total_s = LL * 2 * 4 * 64 * 8;        // 122880
    const int total_o = 2 * 4 * 64 * 8;             // 4096
    const int total = total_c + total_r + total_s + total_o;
    for (int i = blockIdx.x * blockDim.x + threadIdx.x; i < total; i += gridDim.x * blockDim.x) {
        if (i < total_c) {
            int e = i & 7, lane = (i >> 3) & 63, mf = (i >> 9) & 7, rest = i >> 12;
            int ks = rest % 6, l = rest / 6;
            int cin = (ks & 1) * 32 + (lane >> 4) * 8 + e;
            int tap = ks >> 1;
            int cout = mf * 16 + (lane & 15);
            wcv[i] = (f16)conv_w[(((size_t)l * 3 + tap) * 64 + cin) * 128 + cout];
        } else if (i < total_c + total_r) {
            int j = i - total_c;
            int e = j & 7, lane = (j >> 3) & 63, mf = (j >> 9) & 3, kk = (j >> 11) & 1, l = j >> 12;
            int cin = kk * 32 + (lane >> 4) * 8 + e;
            int cout = mf * 16 + (lane & 15);
            wrs[j] = (f16)res_w[((size_t)l * 64 + cin) * 64 + cout];
        } else if (i < total_c + total_r + total_s) {
            int j = i - total_c - total_r;
            int e = j & 7, lane = (j >> 3) & 63, mf = (j >> 9) & 3, kk = (j >> 11) & 1, l = j >> 12;
            int cin = kk * 32 + (lane >> 4) * 8 + e;
            int cout = mf * 16 + (lane & 15);
            wsk[j] = (f16)skip_w[((size_t)l * 64 + cin) * 64 + cout];
        } else {
            int j = i - total_c - total_r - total_s;
            int e = j & 7, lane = (j >> 3) & 63, mf = (j >> 9) & 3, kk = (j >> 11) & 1;
            int cin = kk * 32 + (lane >> 4) * 8 + e;  // k = cout of skip
            int c = mf * 16 + (lane & 15);
            wo0[j] = (f16)out0_w[cin * 64 + c];
        }
    }
}

// ---------------- x0 = relu(signal * in_w + in_b) -> f16 ----------------
__global__ void init_x_kernel(const float* __restrict__ signal, const float* __restrict__ in_w,
                              const float* __restrict__ in_b, f16* __restrict__ x0) {
    int i = blockIdx.x * 256 + threadIdx.x;  // < B*T*8
    int bt = i >> 3, g = i & 7;
    float s = signal[bt];
    f32x4 w0 = *(const f32x4*)&in_w[g * 8];
    f32x4 w1 = *(const f32x4*)&in_w[g * 8 + 4];
    f32x4 b0 = *(const f32x4*)&in_b[g * 8];
    f32x4 b1 = *(const f32x4*)&in_b[g * 8 + 4];
    f16x8 o;
#pragma unroll
    for (int j = 0; j < 4; ++j) {
        o[j] = (f16)fmaxf(s * w0[j] + b0[j], 0.f);
        o[4 + j] = (f16)fmaxf(s * w1[j] + b1[j], 0.f);
    }
    *(f16x8*)&x0[(size_t)bt * CC + g * 8] = o;
}

// ---------------- embed stage 1 (K-split): table + swish(pe0) -> h1[B][512] ----------------
__global__ void embed_stage1(const int* __restrict__ timestep, const float* __restrict__ pe0_w,
                             const float* __restrict__ pe0_b, float* __restrict__ h1) {
    __shared__ float emb[BB * 128];
    __shared__ float red[256];
    const int tid = threadIdx.x;
    for (int i = tid; i < BB * 128; i += 256) {
        int b = i >> 7, j = i & 127, jj = j & 63;
        float logit = (jj == 63) ? 1.0f : (float)jj * (1.0f / 63.0f);
        double e10 = pow(10.0, (double)(4.0f * logit));
        float comp = (float)e10 * (float)timestep[b];
        emb[i] = (j < 64) ? (float)sin((double)comp) : (float)cos((double)comp);
    }
    __syncthreads();
    const int c16 = tid & 15, b = (tid >> 4) & 3, part = tid >> 6;
    const int col = blockIdx.x * 16 + c16;
    float s = 0.f;
#pragma unroll
    for (int j = part * 32; j < part * 32 + 32; ++j)
        s += emb[b * 128 + j] * pe0_w[j * 512 + col];
    red[tid] = s;
    __syncthreads();
    if (part == 0) {
        float x = red[tid] + red[tid + 64] + red[tid + 128] + red[tid + 192] + pe0_b[col];
        h1[b * 512 + col] = x * fsig(x);
    }
}

// ---------------- embed stage 2 (K-split): swish(pe1) -> embed2[B][512] ----------------
__global__ void embed_stage2(const float* __restrict__ h1, const float* __restrict__ pe1_w,
                             const float* __restrict__ pe1_b, float* __restrict__ embed2) {
    __shared__ float hs[BB * 512];
    __shared__ float red[256];
    const int tid = threadIdx.x;
    for (int i = tid; i < BB * 512; i += 256) hs[i] = h1[i];
    __syncthreads();
    const int c8 = tid & 7, b = (tid >> 3) & 3, part = tid >> 5;
    const int col = blockIdx.x * 8 + c8;
    float s = 0.f;
#pragma unroll
    for (int j = part * 64; j < part * 64 + 64; ++j)
        s += hs[b * 512 + j] * pe1_w[j * 512 + col];
    red[tid] = s;
    __syncthreads();
    if (part == 0) {
        float x = pe1_b[col];
#pragma unroll
        for (int ph = 0; ph < 8; ++ph) x += red[ph * 32 + (tid & 31)];
        embed2[b * 512 + col] = x * fsig(x);
    }
}

// ---------------- e[l][b][64] = embed2[b] @ blk_emb_w[l] + blk_emb_b[l] ----------------
__global__ void e_kernel(const float* __restrict__ embed2, const float* __restrict__ blk_emb_w,
                         const float* __restrict__ blk_emb_b, float* __restrict__ e_out) {
    const int l = blockIdx.x, b = blockIdx.y;
    const int tid = threadIdx.x;
    __shared__ float em[512];
    __shared__ float red[256];
    for (int i = tid; i < 512; i += 256) em[i] = embed2[b * 512 + i];
    __syncthreads();
    const int c = tid & 63, part = tid >> 6;
    float s0 = 0.f, s1 = 0.f;
    for (int j = part * 128; j < part * 128 + 128; j += 2) {
        s0 += em[j] * blk_emb_w[((size_t)l * 512 + j) * 64 + c];
        s1 += em[j + 1] * blk_emb_w[((size_t)l * 512 + j + 1) * 64 + c];
    }
    red[tid] = s0 + s1;
    __syncthreads();
    if (tid < 64)
        e_out[(l * BB + b) * 64 + tid] =
            red[tid] + red[tid + 64] + red[tid + 128] + red[tid + 192] + blk_emb_b[l * 64 + tid];
}

// ---------------- evec[l][b][tap][128] = e @ conv_w[l][tap] (+conv_b at tap1) ----------------
__global__ void evec2_kernel(const float* __restrict__ e_in, const float* __restrict__ conv_w,
                             const float* __restrict__ conv_b, float* __restrict__ evec) {
    const int l = blockIdx.x, tap = blockIdx.y, b = blockIdx.z;
    const int n = threadIdx.x;  // 0..127
    __shared__ float es[64];
    if (n < 64) es[n] = e_in[(l * BB + b) * 64 + n];
    __syncthreads();
    const float* cw = conv_w + ((size_t)(l * 3 + tap) * 64) * 128;
    float a0 = 0.f, a1 = 0.f, a2 = 0.f, a3 = 0.f;
#pragma unroll
    for (int k = 0; k < 64; k += 4) {
        a0 += es[k] * cw[k * 128 + n];
        a1 += es[k + 1] * cw[(k + 1) * 128 + n];
        a2 += es[k + 2] * cw[(k + 2) * 128 + n];
        a3 += es[k + 3] * cw[(k + 3) * 128 + n];
    }
    float s = a0 + a1 + a2 + a3 + ((tap == 1) ? conv_b[l * 128 + n] : 0.f);
    evec[((size_t)(l * 4 + b) * 3 + tap) * 128 + n] = s;
}

// ---------------- sum of skip biases over layers ----------------
__global__ void sbsum_kernel(const float* __restrict__ skip_b, float* __restrict__ sbsum) {
    int c = threadIdx.x;  // 64
    float s = 0.f;
    for (int l = 0; l < LL; ++l) s += skip_b[l * 64 + c];
    sbsum[c] = s;
}

// ---------------- single-layer kernel (round-16 proven: 64 rows, XCD swizzle) ----------------
__launch_bounds__(256, 5)
__global__ void layer_kernel(const f16* __restrict__ xin, f16* __restrict__ xout,
                             f16* __restrict__ zg,
                             const f16* __restrict__ wcv, const f16* __restrict__ wrs,
                             const float* __restrict__ evec_l, const float* __restrict__ res_b,
                             const f16* __restrict__ zpage, int d) {
    extern __shared__ f16 lds[];
    const int tid = threadIdx.x, lane = tid & 63, w = tid >> 6;
    const int lrow = lane & 15, lk = lane >> 4;
    const int lin = blockIdx.x;
    const int lin2 = (lin & 7) * 128 + (lin >> 3);
    const int b = lin2 >> 8, t0 = (lin2 & 255) * 64;
    const int stride = (d < 64) ? d : 64;
    const int R8 = (64 + 2 * stride + 7) & ~7;
    f16* xs = lds;
    f16* zs = lds + R8 * 64;
    const f16* xb = xin + (size_t)b * TT * CC;
    f16* zb = zg + (size_t)b * TT * CC;

    const int NCH = R8 >> 3;
    for (int chunk = w; chunk < NCH; chunk += 4) {
        int gid = chunk * 64 + lane;
        int r = gid >> 3, g = gid & 7;
        int t = t0 - d + r + ((d > 64) ? ((r >> 6) * (d - 64)) : 0);
        const f16* src = ((unsigned)t < TT) ? (xb + (size_t)t * CC + ((g ^ (r & 7)) << 3)) : zpage;
        gl_lds16(src, (void*)((char*)xs + chunk * 1024));
    }
    __syncthreads();

    f32x4 acc[2][4] = {};
#pragma unroll
    for (int ks = 0; ks < 6; ++ks) {
        const int tap = ks >> 1, kk = ks & 1;
        f16x8 aw0 = *(const f16x8*)&wcv[((ks * 8 + w) * 64 + lane) * 8];
        f16x8 aw1 = *(const f16x8*)&wcv[((ks * 8 + w + 4) * 64 + lane) * 8];
#pragma unroll
        for (int nfi = 0; nfi < 4; ++nfi) {
            int r = nfi * 16 + lrow + tap * stride;
            int g = kk * 4 + lk;
            f16x8 bx = *(const f16x8*)&xs[r * 64 + ((g ^ (r & 7)) << 3)];
            acc[0][nfi] = MFMA(aw0, bx, acc[0][nfi]);
            acc[1][nfi] = MFMA(aw1, bx, acc[1][nfi]);
        }
    }

    const float* evb = evec_l + b * 384;
    const int ca = w * 16 + lk * 4;
    const int gz = ca >> 3;
    f32x4 e0a = *(const f32x4*)&evb[ca], e1a = *(const f32x4*)&evb[128 + ca],
          e2a = *(const f32x4*)&evb[256 + ca];
    f32x4 e0b = *(const f32x4*)&evb[64 + ca], e1b = *(const f32x4*)&evb[192 + ca],
          e2b = *(const f32x4*)&evb[320 + ca];
#pragma unroll
    for (int nfi = 0; nfi < 4; ++nfi) {
        int trow = nfi * 16 + lrow;
        int t = t0 + trow;
        float m0 = (t >= d) ? 1.f : 0.f;
        float m2 = (t + d < TT) ? 1.f : 0.f;
        f16x4 zo;
#pragma unroll
        for (int r = 0; r < 4; ++r) {
            float ya = acc[0][nfi][r] + e1a[r] + m0 * e0a[r] + m2 * e2a[r];
            float yb = acc[1][nfi][r] + e1b[r] + m0 * e0b[r] + m2 * e2b[r];
            zo[r] = (f16)(ftanhf(ya) * fsig(yb));
        }
        *(f16x4*)&zs[trow * 64 + ((gz ^ (trow & 7)) << 3) + (ca & 7)] = zo;
        *(f16x4*)&zb[(size_t)(t0 + trow) * CC + ca] = zo;
    }

    if (wrs != nullptr) {
        __syncthreads();
        f32x4 accR[4] = {};
#pragma unroll
        for (int kk = 0; kk < 2; ++kk) {
            f16x8 ar_ = *(const f16x8*)&wrs[((kk * 4 + w) * 64 + lane) * 8];
#pragma unroll
            for (int nfi = 0; nfi < 4; ++nfi) {
                int trow = nfi * 16 + lrow;
                int g = kk * 4 + lk;
                f16x8 bz = *(const f16x8*)&zs[trow * 64 + ((g ^ (trow & 7)) << 3)];
                accR[nfi] = MFMA(ar_, bz, accR[nfi]);
            }
        }
        f16* xob = xout + (size_t)b * TT * CC;
        f32x4 rb4 = *(const f32x4*)&res_b[ca];
#pragma unroll
        for (int nfi = 0; nfi < 4; ++nfi) {
            int trow = nfi * 16 + lrow;
            int rr = stride + trow;
            f16x4 xv = *(const f16x4*)&xs[rr * 64 + ((gz ^ (rr & 7)) << 3) + (ca & 7)];
            f16x4 xo;
#pragma unroll
            for (int r = 0; r < 4; ++r)
                xo[r] = (f16)((accR[nfi][r] + rb4[r] + (float)xv[r]) * 0.70710678118654752f);
            *(f16x4*)&xob[(size_t)(t0 + trow) * CC + ca] = xo;
        }
    }
}

// ---------------- fused 2-layer pair kernel (small dilations D1, D2) ----------------
template <int D1, int D2>
__launch_bounds__(256, 4)
__global__ void pair_kernel(const f16* __restrict__ xin, f16* __restrict__ xout,
                            f16* __restrict__ zg1, f16* __restrict__ zg2,
                            const f16* __restrict__ wcv1, const f16* __restrict__ wcv2,
                            const f16* __restrict__ wrs1, const f16* __restrict__ wrs2,
                            const float* __restrict__ evec1, const float* __restrict__ evec2,
                            const float* __restrict__ resb1, const float* __restrict__ resb2,
                            const f16* __restrict__ zpage) {
    constexpr int H = D1 + D2;
    constexpr int RX = 64 + 2 * H;
    constexpr int R8X = (RX + 7) & ~7;
    constexpr int NT = (RX + 15) / 16;
    constexpr int ZR = NT * 16;
    __shared__ f16 xs[R8X * 64];
    __shared__ f16 zs[ZR * 64];
    __shared__ f16 xn[ZR * 64];
    f16* z2 = xs;  // alias: x dead after res-i phase

    const int tid = threadIdx.x, lane = tid & 63, w = tid >> 6;
    const int lrow = lane & 15, lk = lane >> 4;
    const int lin = blockIdx.x;  // 1024 = 8 XCD x 128
    const int lin2 = (lin & 7) * 128 + (lin >> 3);
    const int b = lin2 >> 8, t0 = (lin2 & 255) * 64;
    const f16* xb = xin + (size_t)b * TT * CC;
    f16* zb1 = zg1 + (size_t)b * TT * CC;
    f16* zb2 = zg2 + (size_t)b * TT * CC;
    f16* xob = xout + (size_t)b * TT * CC;
    const int ca = w * 16 + lk * 4, gz = ca >> 3;

    const int NCH = R8X >> 3;
    for (int chunk = w; chunk < NCH; chunk += 4) {
        int gid = chunk * 64 + lane;
        int r = gid >> 3, g = gid & 7;
        int t = t0 - H + r;
        const f16* src = ((unsigned)t < TT) ? (xb + (size_t)t * CC + ((g ^ (r & 7)) << 3)) : zpage;
        gl_lds16(src, (void*)((char*)xs + chunk * 1024));
    }
    __syncthreads();

    {
        f32x4 acc[2][NT] = {};
#pragma unroll
        for (int ks = 0; ks < 6; ++ks) {
            const int tap = ks >> 1, kk = ks & 1;
            f16x8 aw0 = *(const f16x8*)&wcv1[((ks * 8 + w) * 64 + lane) * 8];
            f16x8 aw1 = *(const f16x8*)&wcv1[((ks * 8 + w + 4) * 64 + lane) * 8];
#pragma unroll
            for (int nfi = 0; nfi < NT; ++nfi) {
                int rx = nfi * 16 + lrow + (tap - 1) * D1;
                rx = (rx < 0) ? 0 : ((rx > R8X - 1) ? (R8X - 1) : rx);
                int g = kk * 4 + lk;
                f16x8 bx = *(const f16x8*)&xs[rx * 64 + ((g ^ (rx & 7)) << 3)];
                acc[0][nfi] = MFMA(aw0, bx, acc[0][nfi]);
                acc[1][nfi] = MFMA(aw1, bx, acc[1][nfi]);
            }
        }
        const float* evb = evec1 + b * 384;
        f32x4 e0a = *(const f32x4*)&evb[ca], e1a = *(const f32x4*)&evb[128 + ca],
              e2a = *(const f32x4*)&evb[256 + ca];
        f32x4 e0b = *(const f32x4*)&evb[64 + ca], e1b = *(const f32x4*)&evb[192 + ca],
              e2b = *(const f32x4*)&evb[320 + ca];
#pragma unroll
        for (int nfi = 0; nfi < NT; ++nfi) {
            int rt = nfi * 16 + lrow;
            int tz = t0 - H + rt;
            bool valid = ((unsigned)tz < TT);
            float m0 = (tz >= D1) ? 1.f : 0.f;
            float m2 = (tz + D1 < TT) ? 1.f : 0.f;
            f16x4 zo;
#pragma unroll
            for (int r = 0; r < 4; ++r) {
                float ya = acc[0][nfi][r] + e1a[r] + m0 * e0a[r] + m2 * e2a[r];
                float yb = acc[1][nfi][r] + e1b[r] + m0 * e0b[r] + m2 * e2b[r];
                zo[r] = valid ? (f16)(ftanhf(ya) * fsig(yb)) : (f16)0;
            }
            *(f16x4*)&zs[rt * 64 + ((gz ^ (rt & 7)) << 3) + (ca & 7)] = zo;
            if (rt >= H && rt < H + 64) *(f16x4*)&zb1[(size_t)tz * CC + ca] = zo;
        }
    }
    __syncthreads();

    {
        f32x4 accR[NT] = {};
#pragma unroll
        for (int kk = 0; kk < 2; ++kk) {
            f16x8 ar_ = *(const f16x8*)&wrs1[((kk * 4 + w) * 64 + lane) * 8];
#pragma unroll
            for (int nfi = 0; nfi < NT; ++nfi) {
                int rt = nfi * 16 + lrow;
                int g = kk * 4 + lk;
                f16x8 bz = *(const f16x8*)&zs[rt * 64 + ((g ^ (rt & 7)) << 3)];
                accR[nfi] = MFMA(ar_, bz, accR[nfi]);
            }
        }
        f32x4 rb4 = *(const f32x4*)&resb1[ca];
#pragma unroll
        for (int nfi = 0; nfi < NT; ++nfi) {
            int rt = nfi * 16 + lrow;
            int tz = t0 - H + rt;
            bool valid = ((unsigned)tz < TT);
            int rxc = (rt > R8X - 1) ? (R8X - 1) : rt;
            f16x4 xv = *(const f16x4*)&xs[rxc * 64 + ((gz ^ (rxc & 7)) << 3) + (ca & 7)];
            f16x4 xo;
#pragma unroll
            for (int r = 0; r < 4; ++r)
                xo[r] = valid ? (f16)((accR[nfi][r] + rb4[r] + (float)xv[r]) * 0.70710678118654752f)
                              : (f16)0;
            *(f16x4*)&xn[rt * 64 + ((gz ^ (rt & 7)) << 3) + (ca & 7)] = xo;
        }
    }
    __syncthreads();

    {
        f32x4 acc[2][4] = {};
#pragma unroll
        for (int ks = 0; ks < 6; ++ks) {
            const int tap = ks >> 1, kk = ks & 1;
            f16x8 aw0 = *(const f16x8*)&wcv2[((ks * 8 + w) * 64 + lane) * 8];
            f16x8 aw1 = *(const f16x8*)&wcv2[((ks * 8 + w + 4) * 64 + lane) * 8];
#pragma unroll
            for (int nfi = 0; nfi < 4; ++nfi) {
                int rxn = nfi * 16 + lrow + H + (tap - 1) * D2;
                int g = kk * 4 + lk;
                f16x8 bx = *(const f16x8*)&xn[rxn * 64 + ((g ^ (rxn & 7)) << 3)];
                acc[0][nfi] = MFMA(aw0, bx, acc[0][nfi]);
                acc[1][nfi] = MFMA(aw1, bx, acc[1][nfi]);
            }
        }
        const float* evb = evec2 + b * 384;
        f32x4 e0a = *(const f32x4*)&evb[ca], e1a = *(const f32x4*)&evb[128 + ca],
              e2a = *(const f32x4*)&evb[256 + ca];
        f32x4 e0b = *(const f32x4*)&evb[64 + ca], e1b = *(const f32x4*)&evb[192 + ca],
              e2b = *(const f32x4*)&evb[320 + ca];
#pragma unroll
        for (int nfi = 0; nfi < 4; ++nfi) {
            int trow = nfi * 16 + lrow;
            int t = t0 + trow;
            float m0 = (t >= D2) ? 1.f : 0.f;
            float m2 = (t + D2 < TT) ? 1.f : 0.f;
            f16x4 zo;
#pragma unroll
            for (int r = 0; r < 4; ++r) {
                float ya = acc[0][nfi][r] + e1a[r] + m0 * e0a[r] + m2 * e2a[r];
                float yb = acc[1][nfi][r] + e1b[r] + m0 * e0b[r] + m2 * e2b[r];
                zo[r] = (f16)(ftanhf(ya) * fsig(yb));
            }
            *(f16x4*)&z2[trow * 64 + ((gz ^ (trow & 7)) << 3) + (ca & 7)] = zo;
            *(f16x4*)&zb2[(size_t)t * CC + ca] = zo;
        }
    }
    __syncthreads();

    {
        f32x4 accR[4] = {};
#pragma unroll
        for (int kk = 0; kk < 2; ++kk) {
            f16x8 ar_ = *(const f16x8*)&wrs2[((kk * 4 + w) * 64 + lane) * 8];
#pragma unroll
            for (int nfi = 0; nfi < 4; ++nfi) {
                int trow = nfi * 16 + lrow;
                int g = kk * 4 + lk;
                f16x8 bz = *(const f16x8*)&z2[trow * 64 + ((g ^ (trow & 7)) << 3)];
                accR[nfi] = MFMA(ar_, bz, accR[nfi]);
            }
        }
        f32x4 rb4 = *(const f32x4*)&resb2[ca];
#pragma unroll
        for (int nfi = 0; nfi < 4; ++nfi) {
            int trow = nfi * 16 + lrow;
            int rr = trow + H;
            f16x4 xv = *(const f16x4*)&xn[rr * 64 + ((gz ^ (rr & 7)) << 3) + (ca & 7)];
            f16x4 xo;
#pragma unroll
            for (int r = 0; r < 4; ++r)
                xo[r] = (f16)((accR[nfi][r] + rb4[r] + (float)xv[r]) * 0.70710678118654752f);
            *(f16x4*)&xob[(size_t)(t0 + trow) * CC + ca] = xo;
        }
    }
}

// ---------------- deferred skip reduction + output head (round-13 proven) ----------------
__launch_bounds__(256)
__global__ void skip_head(const f16* __restrict__ zbuf, const f16* __restrict__ z29,
                          const f16* __restrict__ wsk, const f16* __restrict__ wo0,
                          const float* __restrict__ sbsum, const float* __restrict__ out0_b,
                          const float* __restrict__ out1_w, const float* __restrict__ out1_b,
                          float* __restrict__ out) {
    __shared__ f16 zb[2][64 * 64];
    const int tid = threadIdx.x, lane = tid & 63, w = tid >> 6;
    const int lrow = lane & 15, lk = lane >> 4;
    const int lin = blockIdx.x;  // 1024 = 8 XCD x 128
    const int lin2 = (lin & 7) * 128 + (lin >> 3);
    const int b = lin2 >> 8, tile = lin2 & 255;
    const int t0 = tile * 64;

#define STAGE_Z(L, BUF)                                                                       \
    {                                                                                         \
        const f16* zl =                                                                       \
            (((L) < LL - 1) ? (zbuf + (size_t)(L)*BB * TT * CC) : z29) + (size_t)b * TT * CC; \
        _Pragma("unroll") for (int j = 0; j < 2; ++j) {                                       \
            int chunk = j * 4 + w;                                                            \
            int gid = chunk * 64 + lane;                                                      \
            int r = gid >> 3, g = gid & 7;                                                    \
            gl_lds16(zl + (size_t)(t0 + r) * CC + ((g ^ (r & 7)) << 3),                       \
                     (void*)((char*)zb[BUF] + chunk * 1024));                                 \
        }                                                                                     \
    }

    f32x4 accS[4] = {};
    STAGE_Z(0, 0);
    for (int l = 0; l < LL; ++l) {
        __syncthreads();
        if (l + 1 < LL) STAGE_Z(l + 1, (l + 1) & 1);
        const f16* wl = wsk + (size_t)l * 4096;
        const f16* zcur = zb[l & 1];
#pragma unroll
        for (int kk = 0; kk < 2; ++kk) {
            f16x8 as_ = *(const f16x8*)&wl[((kk * 4 + w) * 64 + lane) * 8];
#pragma unroll
            for (int nt = 0; nt < 4; ++nt) {
                int trow = nt * 16 + lrow;
                int g = kk * 4 + lk;
                f16x8 bz = *(const f16x8*)&zcur[trow * 64 + ((g ^ (trow & 7)) << 3)];
                accS[nt] = MFMA(as_, bz, accS[nt]);
            }
        }
    }

    __syncthreads();
    const float invL = 0.18257418583505537f;  // 1/sqrt(30)
    const int cb = w * 16 + lk * 4;
    const int gz = cb >> 3;
    f32x4 sb4 = *(const f32x4*)&sbsum[cb];
#pragma unroll
    for (int nt = 0; nt < 4; ++nt) {
        int row = nt * 16 + lrow;
        f16x4 sn;
#pragma unroll
        for (int r = 0; r < 4; ++r) sn[r] = (f16)((accS[nt][r] + sb4[r]) * invL);
        *(f16x4*)&zb[0][row * 64 + ((gz ^ (row & 7)) << 3) + (cb & 7)] = sn;
    }
    __syncthreads();

    const int trow = w * 16 + lrow;
    f32x4 accO[4] = {};
#pragma unroll
    for (int kk = 0; kk < 2; ++kk) {
        int g = kk * 4 + lk;
        f16x8 bz = *(const f16x8*)&zb[0][trow * 64 + ((g ^ (trow & 7)) << 3)];
#pragma unroll
        for (int mf = 0; mf < 4; ++mf) {
            f16x8 aw = *(const f16x8*)&wo0[((kk * 4 + mf) * 64 + lane) * 8];
            accO[mf] = MFMA(aw, bz, accO[mf]);
        }
    }
    float pv = 0.f;
    const float b1 = out1_b[0];
#pragma unroll
    for (int mf = 0; mf < 4; ++mf) {
        int c = mf * 16 + lk * 4;
        f32x4 b0 = *(const f32x4*)&out0_b[c];
        f32x4 w1 = *(const f32x4*)&out1_w[c];
#pragma unroll
        for (int r = 0; r < 4; ++r) pv += fmaxf(accO[mf][r] + b0[r], 0.f) * w1[r];
    }
    pv += __shfl_xor(pv, 16);
    pv += __shfl_xor(pv, 32);
    if (lane < 16) out[(size_t)b * TT + t0 + w * 16 + lane] = pv + b1;
#undef STAGE_Z
}

extern "C" void kernel_launch(void* const* d_in, const int* in_sizes, int n_in,
                              void* d_out, int out_size, void* d_ws, size_t ws_size,
                              hipStream_t stream) {
    const float* signal = (const float*)d_in[0];
    const int* timestep = (const int*)d_in[1];
    const float* in_w = (const float*)d_in[2];
    const float* in_b = (const float*)d_in[3];
    const float* pe0_w = (const float*)d_in[4];
    const float* pe0_b = (const float*)d_in[5];
    const float* pe1_w = (const float*)d_in[6];
    const float* pe1_b = (const float*)d_in[7];
    const float* blk_emb_w = (const float*)d_in[8];
    const float* blk_emb_b = (const float*)d_in[9];
    const float* blk_conv_w = (const float*)d_in[10];
    const float* blk_conv_b = (const float*)d_in[11];
    const float* blk_res_w = (const float*)d_in[12];
    const float* blk_res_b = (const float*)d_in[13];
    const float* blk_skip_w = (const float*)d_in[14];
    const float* blk_skip_b = (const float*)d_in[15];
    const float* out0_w = (const float*)d_in[16];
    const float* out0_b = (const float*)d_in[17];
    const float* out1_w = (const float*)d_in[18];
    const float* out1_b = (const float*)d_in[19];

    char* p = (char*)d_ws;
    const size_t xhsz = (size_t)BB * TT * CC * sizeof(f16);  // 8 MiB
    const size_t BTC = (size_t)BB * TT * CC;
    f16* xa = (f16*)p; p += xhsz;
    f16* xb2 = (f16*)p; p += xhsz;
    f16* wcv = (f16*)p; p += (size_t)737280 * 2;
    f16* wrs = (f16*)p; p += (size_t)118784 * 2;
    f16* wsk = (f16*)p; p += (size_t)122880 * 2;
    f16* wo0 = (f16*)p; p += (size_t)4096 * 2;
    float* h1 = (float*)p; p += 4 * 512 * sizeof(float);
    float* embed2 = (float*)p; p += 4 * 512 * sizeof(float);
    float* e_buf = (float*)p; p += (size_t)LL * BB * 64 * sizeof(float);
    float* evec = (float*)p; p += (size_t)LL * 4 * 3 * 128 * sizeof(float);
    float* sbsum = (float*)p; p += 64 * sizeof(float);
    f16* zpage = (f16*)p; p += 256;
    p = (char*)(((size_t)p + 255) & ~(size_t)255);
    f16* zbuf = (f16*)p; p += (size_t)(LL - 1) * xhsz;  // layers 0..28; layer 29's z -> dead buf

    hipMemsetAsync(zpage, 0, 256, stream);
    pack_weights<<<1024, 256, 0, stream>>>(blk_conv_w, blk_res_w, blk_skip_w, out0_w,
                                           wcv, wrs, wsk, wo0);
    init_x_kernel<<<2048, 256, 0, stream>>>(signal, in_w, in_b, xa);
    embed_stage1<<<32, 256, 0, stream>>>(timestep, pe0_w, pe0_b, h1);
    embed_stage2<<<64, 256, 0, stream>>>(h1, pe1_w, pe1_b, embed2);
    e_kernel<<<dim3(LL, BB), 256, 0, stream>>>(embed2, blk_emb_w, blk_emb_b, e_buf);
    evec2_kernel<<<dim3(LL, 3, BB), 128, 0, stream>>>(e_buf, blk_conv_w, blk_conv_b, evec);
    sbsum_kernel<<<1, 64, 0, stream>>>(blk_skip_b, sbsum);

    f16* cur = xa;
    f16* nxt = xb2;
    f16* z29 = xa;
    for (int c = 0; c < 3; ++c) {
        const int l0 = c * 10;
        pair_kernel<1, 2><<<1024, 256, 0, stream>>>(
            cur, nxt, zbuf + (size_t)l0 * BTC, zbuf + (size_t)(l0 + 1) * BTC,
            wcv + (size_t)l0 * 24576, wcv + (size_t)(l0 + 1) * 24576,
            wrs + (size_t)l0 * 4096, wrs + (size_t)(l0 + 1) * 4096,
            evec + (size_t)l0 * 1536, evec + (size_t)(l0 + 1) * 1536,
            blk_res_b + l0 * 64, blk_res_b + (l0 + 1) * 64, zpage);
        { f16* t = cur; cur = nxt; nxt = t; }
        pair_kernel<4, 8><<<1024, 256, 0, stream>>>(
            cur, nxt, zbuf + (size_t)(l0 + 2) * BTC, zbuf + (size_t)(l0 + 3) * BTC,
            wcv + (size_t)(l0 + 2) * 24576, wcv + (size_t)(l0 + 3) * 24576,
            wrs + (size_t)(l0 + 2) * 4096, wrs + (size_t)(l0 + 3) * 4096,
            evec + (size_t)(l0 + 2) * 1536, evec + (size_t)(l0 + 3) * 1536,
            blk_res_b + (l0 + 2) * 64, blk_res_b + (l0 + 3) * 64, zpage);
        { f16* t = cur; cur = nxt; nxt = t; }
        for (int i = l0 + 4; i < l0 + 10; ++i) {
            int d = 1 << (i % 10);
            bool last = (i == LL - 1);
            f16* zg = last ? nxt : (zbuf + (size_t)i * BTC);
            if (last) z29 = nxt;
            int stride = (d < 64) ? d : 64;
            int R8 = (64 + 2 * stride + 7) & ~7;
            size_t smem = (size_t)(R8 * 64 + 64 * 64) * sizeof(f16);
            layer_kernel<<<BB * (TT / 64), 256, smem, stream>>>(
                cur, nxt, zg, wcv + (size_t)i * 24576,
                last ? nullptr : (wrs + (size_t)i * 4096), evec + (size_t)i * 1536,
                last ? nullptr : (blk_res_b + i * 64), zpage, d);
            if (!last) { f16* t = cur; cur = nxt; nxt = t; }
        }
    }

    skip_head<<<(BB * TT) / 64, 256, 0, stream>>>(zbuf, z29, wsk, wo0, sbsum, out0_b, out1_w,
                                                  out1_b, (float*)d_out);
}